// Round 3
// baseline (42062.186 us; speedup 1.0000x reference)
//
#include <hip/hip_runtime.h>
#include <hip/hip_cooperative_groups.h>

namespace cg = cooperative_groups;

#define T_STEPS 256
#define H_DIM   1024
#define L_CTX   200
#define CTXD    512
#define A_DIM   512
#define G4      4096

// ws offsets (floats)
#define OFF_XWB      0                                  // 256*4096
#define OFF_CTXW     (OFF_XWB    + T_STEPS*G4)          // 200*512
#define OFF_WHT      (OFF_CTXW   + L_CTX*A_DIM)         // 512*1024
#define OFF_WHHT     (OFF_WHT    + A_DIM*H_DIM)
#define OFF_WHISTT   (OFF_WHHT   + A_DIM*H_DIM)
#define OFF_HIST     (OFF_WHISTT + A_DIM*H_DIM)         // 256*1024
#define OFF_HISTW    (OFF_HIST   + T_STEPS*H_DIM)       // 256*512
#define OFF_Z        (OFF_HISTW  + T_STEPS*A_DIM)       // 4096
#define OFF_U        (OFF_Z      + G4)                  // 512
#define OFF_W        (OFF_U      + A_DIM)               // 512
#define OFF_EC       (OFF_W      + A_DIM)               // 256
#define OFF_EH       (OFF_EC     + 256)                 // 256
#define OFF_CTXV     (OFF_EH     + 256)                 // 512
#define OFF_HCTX     (OFF_CTXV   + CTXD)                // 1024
#define OFF_H        (OFF_HCTX   + H_DIM)               // 1024
#define WS_FLOATS    (OFF_H + H_DIM)

__device__ __forceinline__ float sigmoidf_(float x) { return 1.f / (1.f + __expf(-x)); }

// ---------- prep kernels ----------

// XWb[t][c] = b4[c] + sum_k X[t][k] * Wx[k][c]   (grid: 16 x 32, 256 thr)
__global__ __launch_bounds__(256) void k_xwb(const float* __restrict__ X,
                                             const float* __restrict__ Wx,
                                             const float* __restrict__ b4,
                                             float* __restrict__ XWb) {
    int c  = blockIdx.x * 256 + threadIdx.x;
    int r0 = blockIdx.y * 8;
    float acc[8] = {0,0,0,0,0,0,0,0};
    for (int k = 0; k < 512; ++k) {
        float wv = Wx[k * G4 + c];
        #pragma unroll
        for (int r = 0; r < 8; ++r) acc[r] += X[(r0 + r) * 512 + k] * wv;
    }
    float bb = b4[c];
    #pragma unroll
    for (int r = 0; r < 8; ++r) XWb[(r0 + r) * G4 + c] = acc[r] + bb;
}

// ctxW[l][a] = bctx[a] + sum_k context[l][k] * Wctx[k][a]   (grid: 2 x 25)
__global__ __launch_bounds__(256) void k_ctxw(const float* __restrict__ ctx,
                                              const float* __restrict__ Wctx,
                                              const float* __restrict__ bctx,
                                              float* __restrict__ ctxW) {
    int a  = blockIdx.x * 256 + threadIdx.x;
    int l0 = blockIdx.y * 8;
    float acc[8] = {0,0,0,0,0,0,0,0};
    for (int k = 0; k < 512; ++k) {
        float wv = Wctx[k * A_DIM + a];
        #pragma unroll
        for (int r = 0; r < 8; ++r) acc[r] += ctx[(l0 + r) * CTXD + k] * wv;
    }
    float bb = bctx[a];
    #pragma unroll
    for (int r = 0; r < 8; ++r) ctxW[(l0 + r) * A_DIM + a] = acc[r] + bb;
}

// transpose [1024][512] -> [512][1024]   (grid: 16 x 32, 256 thr)
__global__ __launch_bounds__(256) void k_tr(const float* __restrict__ in,
                                            float* __restrict__ out) {
    __shared__ float tile[32][33];
    int bx = blockIdx.x, by = blockIdx.y;
    int x = threadIdx.x & 31, y4 = threadIdx.x >> 5;
    #pragma unroll
    for (int i = 0; i < 32; i += 8)
        tile[y4 + i][x] = in[(by * 32 + y4 + i) * 512 + bx * 32 + x];
    __syncthreads();
    #pragma unroll
    for (int i = 0; i < 32; i += 8)
        out[(bx * 32 + y4 + i) * 1024 + by * 32 + x] = tile[x][y4 + i];
}

// ---------- cooperative recurrent kernel ----------

struct LP {
    const float *ctx, *Uh, *Cc, *Ph, *Hh;
    const float *c0, *v, *v2, *bv, *bv2, *bhist, *h0;
    const int* parent;
    float* ws;
    float* out;
};

__global__ __launch_bounds__(256) void lstm_loop(LP p) {
    cg::grid_group grid = cg::this_grid();
    const int b    = blockIdx.x;
    const int tid  = threadIdx.x;
    const int lane = tid & 63, wvi = tid >> 6;

    float* XWb    = p.ws + OFF_XWB;
    float* ctxW   = p.ws + OFF_CTXW;
    float* WhT    = p.ws + OFF_WHT;
    float* WhhT   = p.ws + OFF_WHHT;
    float* WhistT = p.ws + OFF_WHISTT;
    float* hist   = p.ws + OFF_HIST;
    float* histW  = p.ws + OFF_HISTW;
    float* z      = p.ws + OFF_Z;
    float* u      = p.ws + OFF_U;
    float* w      = p.ws + OFF_W;
    float* eC     = p.ws + OFF_EC;
    float* eH     = p.ws + OFF_EH;
    float* ctxv   = p.ws + OFF_CTXV;
    float* hctx   = p.ws + OFF_HCTX;
    float* hbuf   = p.ws + OFF_H;

    __shared__ float red[256];
    __shared__ float hs[H_DIM];

    // ---- prologue: u = h0@Wh ; w = h0@Whh + bhist ----
    for (int k = tid; k < H_DIM; k += 256) hs[k] = p.h0[k];
    __syncthreads();
    {
        int d = 4 * b + wvi;  // [0,1024)
        const float* row = (d < A_DIM) ? (WhT + d * H_DIM) : (WhhT + (d - A_DIM) * H_DIM);
        float a = 0.f;
        for (int k = lane; k < H_DIM; k += 64) a += hs[k] * row[k];
        #pragma unroll
        for (int off = 32; off; off >>= 1) a += __shfl_down(a, off);
        if (lane == 0) {
            if (d < A_DIM) u[d] = a;
            else           w[d - A_DIM] = a + p.bhist[d - A_DIM];
        }
        if (b == 0) for (int k = tid; k < H_DIM; k += 256) hbuf[k] = p.h0[k];
    }
    grid.sync();

    const int ci = tid & 15, kg = tid >> 4;
    const int c  = b * 16 + ci;

    for (int t = 0; t < T_STEPS; ++t) {
        // ---------------- P1: GEMV part 1 (h, par_h) + attention logits ----------------
        float acc = 0.f;
        {
            const float* Uc = p.Uh + c;
            const int k0 = kg * 64;
            #pragma unroll 4
            for (int k = k0; k < k0 + 64; ++k) acc += hbuf[k] * Uc[k * G4];
        }
        if (t > 0) {
            const float* ph = hist + p.parent[t] * H_DIM;
            const float* Pc = p.Ph + c;
            const int k0 = kg * 64;
            #pragma unroll 4
            for (int k = k0; k < k0 + 64; ++k) acc += ph[k] * Pc[k * G4];
        }
        if (b < L_CTX) {
            float pp = 0.f;
            for (int i = tid; i < A_DIM; i += 256)
                pp += tanhf(ctxW[b * A_DIM + i] + u[i]) * p.v[i];
            #pragma unroll
            for (int off = 32; off; off >>= 1) pp += __shfl_down(pp, off);
            if (lane == 0) red[wvi] = pp;
            __syncthreads();
            if (tid == 0) eC[b] = red[0] + red[1] + red[2] + red[3] + p.bv[0];
            __syncthreads();
        }
        if (b < t) {
            float pp = 0.f;
            for (int i = tid; i < A_DIM; i += 256)
                pp += tanhf(histW[b * A_DIM + i] + w[i]) * p.v2[i];
            #pragma unroll
            for (int off = 32; off; off >>= 1) pp += __shfl_down(pp, off);
            if (lane == 0) red[wvi] = pp;
            __syncthreads();
            if (tid == 0) eH[b] = red[0] + red[1] + red[2] + red[3] + p.bv2[0];
            __syncthreads();
        }
        grid.sync();  // S1

        // ---------------- P2: softmaxes + weighted sums ----------------
        if (b < 16) {
            float m = -1e30f;
            for (int l = 0; l < L_CTX; ++l) m = fmaxf(m, eC[l]);
            float dsum = 0.f;
            for (int l = 0; l < L_CTX; ++l) dsum += __expf(eC[l] - m);
            const int c2 = b * 32 + (tid & 31), lg = tid >> 5;
            float s = 0.f;
            for (int l = lg; l < L_CTX; l += 8)
                s += __expf(eC[l] - m) * p.ctx[l * CTXD + c2];
            red[tid] = s; __syncthreads();
            if (tid < 32) {
                float tot = 0.f;
                #pragma unroll
                for (int g = 0; g < 8; ++g) tot += red[tid + 32 * g];
                float val = tot / dsum;
                int cc = b * 32 + tid;
                ctxv[cc] = val;
                p.out[T_STEPS * H_DIM + t * CTXD + cc] = val;
            }
        } else if (b < 48) {
            const int cb = (b - 16) * 32;
            if (t == 0) {
                if (tid < 32) hctx[cb + tid] = 0.f;
            } else {
                float m = -1e30f;
                for (int j = 0; j < t; ++j) m = fmaxf(m, eH[j]);
                float dsum = 0.f;
                for (int j = 0; j < t; ++j) dsum += __expf(eH[j] - m);
                const int c2 = cb + (tid & 31), lg = tid >> 5;
                float s = 0.f;
                for (int j = lg; j < t; j += 8)
                    s += __expf(eH[j] - m) * hist[j * H_DIM + c2];
                red[tid] = s; __syncthreads();
                if (tid < 32) {
                    float tot = 0.f;
                    #pragma unroll
                    for (int g = 0; g < 8; ++g) tot += red[tid + 32 * g];
                    hctx[cb + tid] = tot / dsum;
                }
            }
        }
        grid.sync();  // S2

        // ---------------- P3: GEMV part 2 (ctx_vec, h_ctx) + z ----------------
        {
            const float* Ccc = p.Cc + c;
            const int k0 = kg * 32;
            #pragma unroll 4
            for (int k = k0; k < k0 + 32; ++k) acc += ctxv[k] * Ccc[k * G4];
        }
        if (t > 0) {
            const float* Hc = p.Hh + c;
            const int k0 = kg * 64;
            #pragma unroll 4
            for (int k = k0; k < k0 + 64; ++k) acc += hctx[k] * Hc[k * G4];
        }
        red[tid] = acc; __syncthreads();
        #pragma unroll
        for (int sk = 8; sk >= 1; sk >>= 1) {
            if (kg < sk) red[tid] += red[tid + sk * 16];
            __syncthreads();
        }
        if (tid < 16) z[b * 16 + tid] = XWb[t * G4 + b * 16 + tid] + red[tid];
        grid.sync();  // S3

        // ---------------- P4: gates (redundant per block) + u/w/histW dots ----------------
        for (int q = 0; q < 4; ++q) {
            int k = tid + 256 * q;
            float zi = z[k], zf = z[H_DIM + k], zc = z[2 * H_DIM + k], zo = z[3 * H_DIM + k];
            float cn = sigmoidf_(zf) * p.c0[k] + sigmoidf_(zi) * tanhf(zc);
            float hn = sigmoidf_(zo) * tanhf(cn);
            hs[k] = hn;
            if (b == 0) {
                hbuf[k] = hn;
                hist[t * H_DIM + k] = hn;
                p.out[t * H_DIM + k] = hn;
            }
        }
        __syncthreads();
        for (int dd = wvi; dd < 6; dd += 4) {
            int d = 6 * b + dd;  // [0,1536)
            const float* row; float* dst; float bias = 0.f;
            if (d < A_DIM)            { row = WhT    + d * H_DIM;               dst = u + d; }
            else if (d < 2 * A_DIM)   { row = WhhT   + (d - A_DIM) * H_DIM;     dst = w + (d - A_DIM); bias = p.bhist[d - A_DIM]; }
            else                      { row = WhistT + (d - 2 * A_DIM) * H_DIM; dst = histW + t * A_DIM + (d - 2 * A_DIM); }
            float a2 = 0.f;
            for (int k = lane; k < H_DIM; k += 64) a2 += hs[k] * row[k];
            #pragma unroll
            for (int off = 32; off; off >>= 1) a2 += __shfl_down(a2, off);
            if (lane == 0) *dst = a2 + bias;
        }
        grid.sync();  // S4
    }
}

// ---------- host ----------

extern "C" void kernel_launch(void* const* d_in, const int* in_sizes, int n_in,
                              void* d_out, int out_size, void* d_ws, size_t ws_size,
                              hipStream_t stream) {
    // OOB-write insurance: if the harness workspace is smaller than we need,
    // bail out (graceful wrong-answer instead of a GPU memory fault).
    if (ws_size < (size_t)WS_FLOATS * sizeof(float)) return;

    const float* X      = (const float*)d_in[0];
    const float* ctx    = (const float*)d_in[1];
    const float* h0     = (const float*)d_in[2];
    const float* c0     = (const float*)d_in[3];
    const int*   parent = (const int*)  d_in[4];
    const float* Wx     = (const float*)d_in[5];
    const float* Uh     = (const float*)d_in[6];
    const float* Cc     = (const float*)d_in[7];
    const float* Ph     = (const float*)d_in[8];
    const float* Hh     = (const float*)d_in[9];
    const float* b4     = (const float*)d_in[10];
    const float* Wctx   = (const float*)d_in[11];
    const float* bctx   = (const float*)d_in[12];
    const float* Wh     = (const float*)d_in[13];
    const float* v      = (const float*)d_in[14];
    const float* bv     = (const float*)d_in[15];
    const float* Whist  = (const float*)d_in[16];
    const float* bhist  = (const float*)d_in[17];
    const float* Whh    = (const float*)d_in[18];
    const float* v2     = (const float*)d_in[19];
    const float* bv2    = (const float*)d_in[20];
    float* ws  = (float*)d_ws;
    float* out = (float*)d_out;

    hipLaunchKernelGGL(k_xwb,  dim3(16, 32), dim3(256), 0, stream, X,   Wx,   b4,   ws + OFF_XWB);
    hipLaunchKernelGGL(k_ctxw, dim3(2, 25),  dim3(256), 0, stream, ctx, Wctx, bctx, ws + OFF_CTXW);
    hipLaunchKernelGGL(k_tr,   dim3(16, 32), dim3(256), 0, stream, Wh,    ws + OFF_WHT);
    hipLaunchKernelGGL(k_tr,   dim3(16, 32), dim3(256), 0, stream, Whh,   ws + OFF_WHHT);
    hipLaunchKernelGGL(k_tr,   dim3(16, 32), dim3(256), 0, stream, Whist, ws + OFF_WHISTT);

    LP p{ctx, Uh, Cc, Ph, Hh, c0, v, v2, bv, bv2, bhist, h0, parent, ws, out};
    void* args[] = { &p };
    (void)hipLaunchCooperativeKernel((void*)lstm_loop, dim3(256), dim3(256), args, 0, stream);
}

// Round 4
// 32265.567 us; speedup vs baseline: 1.3036x; 1.3036x over previous
//
#include <hip/hip_runtime.h>
#include <hip/hip_cooperative_groups.h>

namespace cg = cooperative_groups;

#define T_STEPS 256
#define H_DIM   1024
#define L_CTX   200
#define CTXD    512
#define A_DIM   512
#define G4      4096
#define KTOT    3584   // 1024 h + 1024 par + 1024 hctx + 512 ctx
#define NBLK    256
#define NTHR    512

typedef __attribute__((ext_vector_type(8))) unsigned short us8;

// ws offsets (floats)
#define OFF_XWB    0                           // 256*4096      = 1048576
#define OFF_CTXW   (OFF_XWB   + T_STEPS*G4)    // 200*512       = 102400
#define OFF_CTXT   (OFF_CTXW  + L_CTX*A_DIM)   // 512*200       = 102400
#define OFF_U      (OFF_CTXT  + CTXD*L_CTX)    // 512
#define OFF_W      (OFF_U     + A_DIM)         // 512
#define OFF_EC     (OFF_W     + A_DIM)         // 256
#define OFF_EH     (OFF_EC    + 256)           // 256
#define OFF_CTXV   (OFF_EH    + 256)           // 512
#define OFF_HCTX   (OFF_CTXV  + CTXD)          // 1024
#define OFF_HBUF   (OFF_HCTX  + H_DIM)         // 1024
#define OFF_HIST   (OFF_HBUF  + H_DIM)         // 256*1024      = 262144
#define OFF_HISTT  (OFF_HIST  + T_STEPS*H_DIM) // 1024*256      = 262144
#define OFF_HISTW  (OFF_HISTT + H_DIM*T_STEPS) // 256*512       = 131072
#define OFF_W4T    (OFF_HISTW + T_STEPS*A_DIM) // 4096*3584 bf16 = 7340032 floats
#define OFF_WT3    (OFF_W4T   + G4*KTOT/2)     // 1536*1024 bf16 = 786432 floats
#define WS_FLOATS  (OFF_WT3   + 1536*H_DIM/2)  // ~10.04M floats = 40.2 MB

__device__ __forceinline__ float sigmoidf_(float x) { return 1.f / (1.f + __expf(-x)); }
__device__ __forceinline__ float bf2f(unsigned short h) { return __uint_as_float((unsigned)h << 16); }
__device__ __forceinline__ unsigned short f2bf(float x) {
    unsigned u = __float_as_uint(x);
    return (unsigned short)((u + 0x7FFFu + ((u >> 16) & 1u)) >> 16);
}

// ---------- prep kernels ----------

// XWb[t][c] = b4[c] + sum_k X[t][k]*Wx[k][c]   grid(16,32), 256 thr
__global__ __launch_bounds__(256) void k_xwb(const float* __restrict__ X,
                                             const float* __restrict__ Wx,
                                             const float* __restrict__ b4,
                                             float* __restrict__ XWb) {
    int c  = blockIdx.x * 256 + threadIdx.x;
    int r0 = blockIdx.y * 8;
    float acc[8] = {0,0,0,0,0,0,0,0};
    for (int k = 0; k < 512; ++k) {
        float wv = Wx[(size_t)k * G4 + c];
        #pragma unroll
        for (int r = 0; r < 8; ++r) acc[r] += X[(r0 + r) * 512 + k] * wv;
    }
    float bb = b4[c];
    #pragma unroll
    for (int r = 0; r < 8; ++r) XWb[(size_t)(r0 + r) * G4 + c] = acc[r] + bb;
}

// ctxW[l][a] = bctx[a] + sum_k context[l][k]*Wctx[k][a]   grid(2,25)
__global__ __launch_bounds__(256) void k_ctxw(const float* __restrict__ ctx,
                                              const float* __restrict__ Wctx,
                                              const float* __restrict__ bctx,
                                              float* __restrict__ ctxW) {
    int a  = blockIdx.x * 256 + threadIdx.x;
    int l0 = blockIdx.y * 8;
    float acc[8] = {0,0,0,0,0,0,0,0};
    for (int k = 0; k < 512; ++k) {
        float wv = Wctx[(size_t)k * A_DIM + a];
        #pragma unroll
        for (int r = 0; r < 8; ++r) acc[r] += ctx[(l0 + r) * CTXD + k] * wv;
    }
    float bb = bctx[a];
    #pragma unroll
    for (int r = 0; r < 8; ++r) ctxW[(l0 + r) * A_DIM + a] = acc[r] + bb;
}

// pack [Uh;Ph;Hh;Cc] -> W4T[col=4d+q][k] bf16.  grid(112, 32, 4), 256 thr
__global__ __launch_bounds__(256) void k_packW4(const float* __restrict__ Uh,
                                                const float* __restrict__ Ph,
                                                const float* __restrict__ Hh,
                                                const float* __restrict__ Cc,
                                                unsigned short* __restrict__ W4T) {
    __shared__ float tile[32][33];
    const int k0 = blockIdx.x * 32, d0 = blockIdx.y * 32, q = blockIdx.z;
    const int x = threadIdx.x & 31, yy = threadIdx.x >> 5;
    const int c = q * 1024 + d0 + x;
    #pragma unroll
    for (int i = 0; i < 32; i += 8) {
        int ka = k0 + yy + i;
        const float* src; int kk;
        if (ka < 1024)      { src = Uh; kk = ka; }
        else if (ka < 2048) { src = Ph; kk = ka - 1024; }
        else if (ka < 3072) { src = Hh; kk = ka - 2048; }
        else                { src = Cc; kk = ka - 3072; }
        tile[yy + i][x] = src[(size_t)kk * G4 + c];
    }
    __syncthreads();
    #pragma unroll
    for (int i = 0; i < 32; i += 8) {
        int dd = yy + i;
        int col = 4 * (d0 + dd) + q;
        W4T[(size_t)col * KTOT + k0 + x] = f2bf(tile[x][dd]);
    }
}

// pack [Wh|Whh|Whist] ([1024][512] each) -> WT3[j][k] bf16. grid(32,16,3)
__global__ __launch_bounds__(256) void k_packW3(const float* __restrict__ Wh,
                                                const float* __restrict__ Whh,
                                                const float* __restrict__ Whist,
                                                unsigned short* __restrict__ WT3) {
    __shared__ float tile[32][33];
    const int k0 = blockIdx.x * 32, c0 = blockIdx.y * 32, s = blockIdx.z;
    const float* S = (s == 0) ? Wh : (s == 1) ? Whh : Whist;
    const int x = threadIdx.x & 31, yy = threadIdx.x >> 5;
    #pragma unroll
    for (int i = 0; i < 32; i += 8)
        tile[yy + i][x] = S[(size_t)(k0 + yy + i) * 512 + c0 + x];
    __syncthreads();
    #pragma unroll
    for (int i = 0; i < 32; i += 8) {
        int dd = yy + i;
        WT3[(size_t)(s * 512 + c0 + dd) * H_DIM + k0 + x] = f2bf(tile[x][dd]);
    }
}

// context [200][512] -> ctxT [512][200] fp32. grid(7,16)
__global__ __launch_bounds__(256) void k_trg(const float* __restrict__ in,
                                             float* __restrict__ out) {
    __shared__ float tile[32][33];
    const int r0 = blockIdx.x * 32, c0 = blockIdx.y * 32;
    const int x = threadIdx.x & 31, yy = threadIdx.x >> 5;
    #pragma unroll
    for (int i = 0; i < 32; i += 8) {
        int r = r0 + yy + i;
        if (r < L_CTX) tile[yy + i][x] = in[(size_t)r * CTXD + c0 + x];
    }
    __syncthreads();
    #pragma unroll
    for (int i = 0; i < 32; i += 8) {
        int dd = yy + i;
        if (r0 + x < L_CTX) out[(size_t)(c0 + dd) * L_CTX + r0 + x] = tile[x][dd];
    }
}

// ---------- cooperative recurrent kernel ----------

struct LP {
    const float *c0, *v, *v2, *bv, *bv2, *bhist, *h0;
    const int* parent;
    float* ws;
    float* out;
};

__global__ __launch_bounds__(NTHR) void lstm_loop(LP p) {
    cg::grid_group grid = cg::this_grid();
    const int b    = blockIdx.x;
    const int tid  = threadIdx.x;
    const int lane = tid & 63, wv = tid >> 6;

    float* XWb   = p.ws + OFF_XWB;
    float* ctxW  = p.ws + OFF_CTXW;
    float* ctxT  = p.ws + OFF_CTXT;
    float* u     = p.ws + OFF_U;
    float* w     = p.ws + OFF_W;
    float* eC    = p.ws + OFF_EC;
    float* eH    = p.ws + OFF_EH;
    float* ctxv  = p.ws + OFF_CTXV;
    float* hctx  = p.ws + OFF_HCTX;
    float* hbuf  = p.ws + OFF_HBUF;
    float* hist  = p.ws + OFF_HIST;
    float* histT = p.ws + OFF_HISTT;
    float* histW = p.ws + OFF_HISTW;
    const unsigned short* W4T = (const unsigned short*)(p.ws + OFF_W4T);
    const unsigned short* WT3 = (const unsigned short*)(p.ws + OFF_WT3);

    __shared__ float xs[KTOT];
    __shared__ float red[NTHR];
    __shared__ float alpha[256];
    __shared__ float zs[16];
    __shared__ float hsl[H_DIM];

    // ---- prologue: u = h0@Wh, w = h0@Whh + bhist ----
    hsl[tid] = p.h0[tid]; hsl[tid + 512] = p.h0[tid + 512];
    __syncthreads();
    if (wv < 4) {
        int j = b * 4 + wv;                       // [0,1024)
        const us8* wr = (const us8*)(WT3 + (size_t)j * H_DIM) + lane * 2;
        us8 a0 = wr[0], a1 = wr[1];
        float s = 0.f;
        #pragma unroll
        for (int k = 0; k < 8; ++k) s += bf2f(a0[k]) * hsl[lane * 16 + k];
        #pragma unroll
        for (int k = 0; k < 8; ++k) s += bf2f(a1[k]) * hsl[lane * 16 + 8 + k];
        #pragma unroll
        for (int off = 32; off; off >>= 1) s += __shfl_down(s, off);
        if (lane == 0) {
            if (j < A_DIM) u[j] = s;
            else           w[j - A_DIM] = s + p.bhist[j - A_DIM];
        }
    }
    if (b == 0) { hbuf[tid] = p.h0[tid]; hbuf[tid + 512] = p.h0[tid + 512]; }
    grid.sync();

    const int ci = tid & 15, kg = tid >> 4;       // 16 cols x 32 k-groups
    const size_t colbase = (size_t)(b * 16);

    for (int t = 0; t < T_STEPS; ++t) {
        // ---------------- P1: attention logits ----------------
        if (b < L_CTX) {
            float e = tanhf(ctxW[b * A_DIM + tid] + u[tid]) * p.v[tid];
            #pragma unroll
            for (int off = 32; off; off >>= 1) e += __shfl_down(e, off);
            if (lane == 0) red[wv] = e;
            __syncthreads();
            if (tid == 0) {
                float s = p.bv[0];
                #pragma unroll
                for (int g = 0; g < 8; ++g) s += red[g];
                eC[b] = s;
            }
            __syncthreads();
        }
        if (b < t) {
            float e = tanhf(histW[b * A_DIM + tid] + w[tid]) * p.v2[tid];
            #pragma unroll
            for (int off = 32; off; off >>= 1) e += __shfl_down(e, off);
            if (lane == 0) red[wv] = e;
            __syncthreads();
            if (tid == 0) {
                float s = p.bv2[0];
                #pragma unroll
                for (int g = 0; g < 8; ++g) s += red[g];
                eH[b] = s;
            }
            __syncthreads();
        }
        grid.sync();  // S1

        // ---------------- P2: softmaxes + weighted sums ----------------
        if (b < 32) {                              // ctx_vec, 16 dims each
            const int d0 = b * 16;
            if (tid < L_CTX) alpha[tid] = eC[tid];
            __syncthreads();
            float m = -1e30f;
            for (int l = 0; l < L_CTX; ++l) m = fmaxf(m, alpha[l]);
            float ds = 0.f;
            for (int l = 0; l < L_CTX; ++l) ds += __expf(alpha[l] - m);
            __syncthreads();
            if (tid < L_CTX) alpha[tid] = __expf(alpha[tid] - m) / ds;
            __syncthreads();
            const int di = tid >> 5, sub = tid & 31;
            float s = 0.f;
            for (int l = sub; l < L_CTX; l += 32)
                s += alpha[l] * ctxT[(size_t)(d0 + di) * L_CTX + l];
            #pragma unroll
            for (int off = 16; off; off >>= 1) s += __shfl_down(s, off, 32);
            if (sub == 0) {
                ctxv[d0 + di] = s;
                p.out[(size_t)T_STEPS * H_DIM + (size_t)t * CTXD + d0 + di] = s;
            }
        } else if (b < 96) {                       // h_ctx, 16 dims each
            const int d0 = (b - 32) * 16;
            if (t == 0) {
                if (tid < 16) hctx[d0 + tid] = 0.f;
            } else {
                if (tid < t) alpha[tid] = eH[tid];
                __syncthreads();
                float m = -1e30f;
                for (int j = 0; j < t; ++j) m = fmaxf(m, alpha[j]);
                float ds = 0.f;
                for (int j = 0; j < t; ++j) ds += __expf(alpha[j] - m);
                __syncthreads();
                if (tid < t) alpha[tid] = __expf(alpha[tid] - m) / ds;
                __syncthreads();
                const int di = tid >> 5, sub = tid & 31;
                float s = 0.f;
                for (int j = sub; j < t; j += 32)
                    s += alpha[j] * histT[(size_t)(d0 + di) * T_STEPS + j];
                #pragma unroll
                for (int off = 16; off; off >>= 1) s += __shfl_down(s, off, 32);
                if (sub == 0) hctx[d0 + di] = s;
            }
        }
        grid.sync();  // S2

        // ---------------- P3: full GEMV + gates + h_new ----------------
        {
            const int pt = p.parent[t];
            for (int i = tid; i < KTOT; i += NTHR) {
                float val;
                if (i < 1024)      val = hbuf[i];
                else if (i < 2048) val = (t > 0) ? hist[(size_t)pt * H_DIM + (i - 1024)] : 0.f;
                else if (i < 3072) val = hctx[i - 2048];
                else               val = ctxv[i - 3072];
                xs[i] = val;
            }
            __syncthreads();

            float acc = 0.f;
            const us8* wp = (const us8*)(W4T + (colbase + ci) * KTOT) + kg * 14;
            const float* xk = xs + kg * 112;
            #pragma unroll
            for (int i = 0; i < 14; ++i) {
                us8 wvv = wp[i];
                #pragma unroll
                for (int j2 = 0; j2 < 8; ++j2)
                    acc += bf2f(wvv[j2]) * xk[i * 8 + j2];
            }
            red[tid] = acc;
            __syncthreads();
            #pragma unroll
            for (int s2 = 16; s2 >= 1; s2 >>= 1) {
                if (kg < s2) red[tid] += red[tid + s2 * 16];
                __syncthreads();
            }
            if (tid < 16) {
                int dl = tid >> 2, q = tid & 3, d = b * 4 + dl;
                zs[tid] = XWb[(size_t)t * G4 + q * 1024 + d] + red[tid];
            }
            __syncthreads();
            if (tid < 4) {
                int d = b * 4 + tid;
                float zi = zs[tid * 4 + 0], zf = zs[tid * 4 + 1];
                float zc = zs[tid * 4 + 2], zo = zs[tid * 4 + 3];
                float cn = sigmoidf_(zf) * p.c0[d] + sigmoidf_(zi) * tanhf(zc);
                float hn = sigmoidf_(zo) * tanhf(cn);
                hbuf[d] = hn;
                hist[(size_t)t * H_DIM + d] = hn;
                histT[(size_t)d * T_STEPS + t] = hn;
                p.out[(size_t)t * H_DIM + d] = hn;
            }
        }
        grid.sync();  // S3

        // ---------------- P4: u/w/histW for next step ----------------
        hsl[tid] = hbuf[tid]; hsl[tid + 512] = hbuf[tid + 512];
        __syncthreads();
        if (wv < 6) {
            int j = b * 6 + wv;                   // [0,1536)
            const us8* wr = (const us8*)(WT3 + (size_t)j * H_DIM) + lane * 2;
            us8 a0 = wr[0], a1 = wr[1];
            float s = 0.f;
            #pragma unroll
            for (int k = 0; k < 8; ++k) s += bf2f(a0[k]) * hsl[lane * 16 + k];
            #pragma unroll
            for (int k = 0; k < 8; ++k) s += bf2f(a1[k]) * hsl[lane * 16 + 8 + k];
            #pragma unroll
            for (int off = 32; off; off >>= 1) s += __shfl_down(s, off);
            if (lane == 0) {
                if (j < A_DIM)            u[j] = s;
                else if (j < 2 * A_DIM)   w[j - A_DIM] = s + p.bhist[j - A_DIM];
                else                      histW[(size_t)t * A_DIM + (j - 2 * A_DIM)] = s;
            }
        }
        grid.sync();  // S4
    }
}

// ---------- host ----------

extern "C" void kernel_launch(void* const* d_in, const int* in_sizes, int n_in,
                              void* d_out, int out_size, void* d_ws, size_t ws_size,
                              hipStream_t stream) {
    if (ws_size < (size_t)WS_FLOATS * sizeof(float)) return;  // OOB insurance

    const float* X      = (const float*)d_in[0];
    const float* ctx    = (const float*)d_in[1];
    const float* h0     = (const float*)d_in[2];
    const float* c0     = (const float*)d_in[3];
    const int*   parent = (const int*)  d_in[4];
    const float* Wx     = (const float*)d_in[5];
    const float* Uh     = (const float*)d_in[6];
    const float* Cc     = (const float*)d_in[7];
    const float* Ph     = (const float*)d_in[8];
    const float* Hh     = (const float*)d_in[9];
    const float* b4     = (const float*)d_in[10];
    const float* Wctx   = (const float*)d_in[11];
    const float* bctx   = (const float*)d_in[12];
    const float* Wh     = (const float*)d_in[13];
    const float* v      = (const float*)d_in[14];
    const float* bv     = (const float*)d_in[15];
    const float* Whist  = (const float*)d_in[16];
    const float* bhist  = (const float*)d_in[17];
    const float* Whh    = (const float*)d_in[18];
    const float* v2     = (const float*)d_in[19];
    const float* bv2    = (const float*)d_in[20];
    float* ws  = (float*)d_ws;
    float* out = (float*)d_out;

    hipLaunchKernelGGL(k_xwb,    dim3(16, 32),     dim3(256), 0, stream, X,   Wx,   b4,   ws + OFF_XWB);
    hipLaunchKernelGGL(k_ctxw,   dim3(2, 25),      dim3(256), 0, stream, ctx, Wctx, bctx, ws + OFF_CTXW);
    hipLaunchKernelGGL(k_trg,    dim3(7, 16),      dim3(256), 0, stream, ctx, ws + OFF_CTXT);
    hipLaunchKernelGGL(k_packW4, dim3(112, 32, 4), dim3(256), 0, stream, Uh, Ph, Hh, Cc,
                       (unsigned short*)(ws + OFF_W4T));
    hipLaunchKernelGGL(k_packW3, dim3(32, 16, 3),  dim3(256), 0, stream, Wh, Whh, Whist,
                       (unsigned short*)(ws + OFF_WT3));

    LP p{c0, v, v2, bv, bv2, bhist, h0, parent, ws, out};
    void* args[] = { &p };
    (void)hipLaunchCooperativeKernel((void*)lstm_loop, dim3(NBLK), dim3(NTHR), args, 0, stream);
}

// Round 7
// 10550.680 us; speedup vs baseline: 3.9867x; 3.0582x over previous
//
#include <hip/hip_runtime.h>

#define T_STEPS 256
#define H_DIM   1024
#define L_CTX   200
#define CTXD    512
#define A_DIM   512
#define G4      4096
#define KTOT    3584   // 1024 h + 1024 par + 1024 hctx + 512 ctx
#define NBLK    64
#define NTHR    1024

typedef __attribute__((ext_vector_type(8))) unsigned short us8;

// ws offsets (floats)
#define OFF_XWB    0                           // 256*4096
#define OFF_CTXW   (OFF_XWB   + T_STEPS*G4)    // 200*512
#define OFF_CTXT   (OFF_CTXW  + L_CTX*A_DIM)   // 512*200
#define OFF_U      (OFF_CTXT  + CTXD*L_CTX)    // 512
#define OFF_W      (OFF_U     + A_DIM)         // 512
#define OFF_EC     (OFF_W     + A_DIM)         // 256
#define OFF_EH     (OFF_EC    + 256)           // 256
#define OFF_CTXV   (OFF_EH    + 256)           // 512
#define OFF_HCTX   (OFF_CTXV  + CTXD)          // 1024
#define OFF_HBUF   (OFF_HCTX  + H_DIM)         // 1024
#define OFF_HIST   (OFF_HBUF  + H_DIM)         // 256*1024
#define OFF_HISTT  (OFF_HIST  + T_STEPS*H_DIM) // 1024*256
#define OFF_HISTW  (OFF_HISTT + H_DIM*T_STEPS) // 256*512
#define OFF_W4T    (OFF_HISTW + T_STEPS*A_DIM) // 4096*3584 bf16
#define OFF_WT3    (OFF_W4T   + G4*KTOT/2)     // 1536*1024 bf16
#define OFF_BAR    (OFF_WT3   + 1536*H_DIM/2)  // 256 floats (barrier counters)
#define WS_FLOATS  (OFF_BAR   + 256)

__device__ __forceinline__ float sigmoidf_(float x) { return 1.f / (1.f + __expf(-x)); }
__device__ __forceinline__ float bf2f(unsigned short h) { return __uint_as_float((unsigned)h << 16); }
__device__ __forceinline__ unsigned short f2bf(float x) {
    unsigned u = __float_as_uint(x);
    return (unsigned short)((u + 0x7FFFu + ((u >> 16) & 1u)) >> 16);
}
// coherent-point (agent-scope) data accesses: bypass non-coherent per-XCD L2
__device__ __forceinline__ float ld_ag(const float* p) {
    return __hip_atomic_load((float*)p, __ATOMIC_RELAXED, __HIP_MEMORY_SCOPE_AGENT);
}
__device__ __forceinline__ void st_ag(float* p, float v) {
    __hip_atomic_store(p, v, __ATOMIC_RELAXED, __HIP_MEMORY_SCOPE_AGENT);
}
__device__ __forceinline__ float wred(float x) {
    #pragma unroll
    for (int off = 32; off; off >>= 1) x += __shfl_down(x, off);
    return x;
}

// generation-based tree barrier, 64 blocks = 8 groups x 8. No cache fences:
// all cross-block data travels via agent-scope atomics.
__device__ __forceinline__ void gbar(unsigned* bar, int b, unsigned ph) {
    __syncthreads();
    if (threadIdx.x == 0) {
        const int g = b & 7;
        unsigned old = __hip_atomic_fetch_add(bar + g * 16, 1u, __ATOMIC_RELAXED, __HIP_MEMORY_SCOPE_AGENT);
        if (old == ph * 8u - 1u) {  // last of my 8-member group
            unsigned old0 = __hip_atomic_fetch_add(bar + 128, 1u, __ATOMIC_RELAXED, __HIP_MEMORY_SCOPE_AGENT);
            if (old0 == ph * 8u - 1u)  // last group -> release
                __hip_atomic_store(bar + 144, ph, __ATOMIC_RELAXED, __HIP_MEMORY_SCOPE_AGENT);
        }
        int spins = 0;
        while (__hip_atomic_load(bar + 144, __ATOMIC_RELAXED, __HIP_MEMORY_SCOPE_AGENT) < ph) {
            __builtin_amdgcn_s_sleep(2);
            if (++spins > 120000) break;  // hang insurance: wrong answer beats dead GPU
        }
    }
    __syncthreads();
}

// ---------- prep kernels (unchanged from round 4) ----------

__global__ __launch_bounds__(256) void k_xwb(const float* __restrict__ X,
                                             const float* __restrict__ Wx,
                                             const float* __restrict__ b4,
                                             float* __restrict__ XWb) {
    int c  = blockIdx.x * 256 + threadIdx.x;
    int r0 = blockIdx.y * 8;
    float acc[8] = {0,0,0,0,0,0,0,0};
    for (int k = 0; k < 512; ++k) {
        float wv = Wx[(size_t)k * G4 + c];
        #pragma unroll
        for (int r = 0; r < 8; ++r) acc[r] += X[(r0 + r) * 512 + k] * wv;
    }
    float bb = b4[c];
    #pragma unroll
    for (int r = 0; r < 8; ++r) XWb[(size_t)(r0 + r) * G4 + c] = acc[r] + bb;
}

__global__ __launch_bounds__(256) void k_ctxw(const float* __restrict__ ctx,
                                              const float* __restrict__ Wctx,
                                              const float* __restrict__ bctx,
                                              float* __restrict__ ctxW) {
    int a  = blockIdx.x * 256 + threadIdx.x;
    int l0 = blockIdx.y * 8;
    float acc[8] = {0,0,0,0,0,0,0,0};
    for (int k = 0; k < 512; ++k) {
        float wv = Wctx[(size_t)k * A_DIM + a];
        #pragma unroll
        for (int r = 0; r < 8; ++r) acc[r] += ctx[(l0 + r) * CTXD + k] * wv;
    }
    float bb = bctx[a];
    #pragma unroll
    for (int r = 0; r < 8; ++r) ctxW[(l0 + r) * A_DIM + a] = acc[r] + bb;
}

__global__ __launch_bounds__(256) void k_packW4(const float* __restrict__ Uh,
                                                const float* __restrict__ Ph,
                                                const float* __restrict__ Hh,
                                                const float* __restrict__ Cc,
                                                unsigned short* __restrict__ W4T) {
    __shared__ float tile[32][33];
    const int k0 = blockIdx.x * 32, d0 = blockIdx.y * 32, q = blockIdx.z;
    const int x = threadIdx.x & 31, yy = threadIdx.x >> 5;
    const int c = q * 1024 + d0 + x;
    #pragma unroll
    for (int i = 0; i < 32; i += 8) {
        int ka = k0 + yy + i;
        const float* src; int kk;
        if (ka < 1024)      { src = Uh; kk = ka; }
        else if (ka < 2048) { src = Ph; kk = ka - 1024; }
        else if (ka < 3072) { src = Hh; kk = ka - 2048; }
        else                { src = Cc; kk = ka - 3072; }
        tile[yy + i][x] = src[(size_t)kk * G4 + c];
    }
    __syncthreads();
    #pragma unroll
    for (int i = 0; i < 32; i += 8) {
        int dd = yy + i;
        int col = 4 * (d0 + dd) + q;
        W4T[(size_t)col * KTOT + k0 + x] = f2bf(tile[x][dd]);
    }
}

__global__ __launch_bounds__(256) void k_packW3(const float* __restrict__ Wh,
                                                const float* __restrict__ Whh,
                                                const float* __restrict__ Whist,
                                                unsigned short* __restrict__ WT3) {
    __shared__ float tile[32][33];
    const int k0 = blockIdx.x * 32, c0 = blockIdx.y * 32, s = blockIdx.z;
    const float* S = (s == 0) ? Wh : (s == 1) ? Whh : Whist;
    const int x = threadIdx.x & 31, yy = threadIdx.x >> 5;
    #pragma unroll
    for (int i = 0; i < 32; i += 8)
        tile[yy + i][x] = S[(size_t)(k0 + yy + i) * 512 + c0 + x];
    __syncthreads();
    #pragma unroll
    for (int i = 0; i < 32; i += 8) {
        int dd = yy + i;
        WT3[(size_t)(s * 512 + c0 + dd) * H_DIM + k0 + x] = f2bf(tile[x][dd]);
    }
}

__global__ __launch_bounds__(256) void k_trg(const float* __restrict__ in,
                                             float* __restrict__ out) {
    __shared__ float tile[32][33];
    const int r0 = blockIdx.x * 32, c0 = blockIdx.y * 32;
    const int x = threadIdx.x & 31, yy = threadIdx.x >> 5;
    #pragma unroll
    for (int i = 0; i < 32; i += 8) {
        int r = r0 + yy + i;
        if (r < L_CTX) tile[yy + i][x] = in[(size_t)r * CTXD + c0 + x];
    }
    __syncthreads();
    #pragma unroll
    for (int i = 0; i < 32; i += 8) {
        int dd = yy + i;
        if (r0 + x < L_CTX) out[(size_t)(c0 + dd) * L_CTX + r0 + x] = tile[x][dd];
    }
}

// ---------- persistent recurrent kernel (64 blocks x 1024 threads) ----------

struct LP {
    const float *c0, *v, *v2, *bv, *bv2, *bhist, *h0;
    const int* parent;
    float* ws;
    float* out;
};

__global__ __launch_bounds__(NTHR) void lstm_loop(LP p) {
    const int b    = blockIdx.x;
    const int tid  = threadIdx.x;
    const int lane = tid & 63, wv = tid >> 6;   // 16 waves

    float* XWb   = p.ws + OFF_XWB;
    float* ctxW  = p.ws + OFF_CTXW;
    float* ctxT  = p.ws + OFF_CTXT;
    float* u     = p.ws + OFF_U;
    float* w     = p.ws + OFF_W;
    float* eC_g  = p.ws + OFF_EC;
    float* eH_g  = p.ws + OFF_EH;
    float* ctxv  = p.ws + OFF_CTXV;
    float* hctx  = p.ws + OFF_HCTX;
    float* hbuf  = p.ws + OFF_HBUF;
    float* hist  = p.ws + OFF_HIST;
    float* histT = p.ws + OFF_HISTT;
    float* histW = p.ws + OFF_HISTW;
    const unsigned short* W4T = (const unsigned short*)(p.ws + OFF_W4T);
    const unsigned short* WT3 = (const unsigned short*)(p.ws + OFF_WT3);
    unsigned* bar = (unsigned*)(p.ws + OFF_BAR);

    __shared__ float xs[KTOT];       // GEMV input vector (h | par | hctx | ctx)
    __shared__ float red[NTHR];
    __shared__ float aC[256], aH[256];
    __shared__ float us_[512], ws_[512], vs_[512], v2s_[512];
    __shared__ float sc[4];

    // stage constants v, v2
    if (tid < 512) vs_[tid] = p.v[tid]; else v2s_[tid - 512] = p.v2[tid - 512];
    // stage h0 for prologue dots
    xs[tid] = p.h0[tid];
    __syncthreads();

    // ---- prologue: u = Wh^T h0 ; w = Whh^T h0 + bhist ----
    {
        int j = b * 16 + wv;                       // [0,1024)
        const us8* wr = (const us8*)(WT3 + (size_t)j * H_DIM) + lane * 2;
        us8 a0 = wr[0], a1 = wr[1];
        float s = 0.f;
        #pragma unroll
        for (int k = 0; k < 8; ++k) s += bf2f(a0[k]) * xs[lane * 16 + k];
        #pragma unroll
        for (int k = 0; k < 8; ++k) s += bf2f(a1[k]) * xs[lane * 16 + 8 + k];
        s = wred(s);
        if (lane == 0) {
            if (j < A_DIM) st_ag(u + j, s);
            else           st_ag(w + j - A_DIM, s + p.bhist[j - A_DIM]);
        }
        if (b == 0) st_ag(hbuf + tid, p.h0[tid]);
    }
    unsigned ph = 1;
    gbar(bar, b, ph++);

    for (int t = 0; t < T_STEPS; ++t) {
        // ---------------- P1: attention logits ----------------
        if (tid < 512) us_[tid] = ld_ag(u + tid);
        else           ws_[tid - 512] = ld_ag(w + tid - 512);
        __syncthreads();
        {
            const int idx = b * 16 + wv;           // [0,1024)
            if (idx < L_CTX) {
                const float4* cw = (const float4*)(ctxW + (size_t)idx * A_DIM) + lane * 2;
                float4 c0v = cw[0], c1v = cw[1];
                const int i0 = lane * 8;
                float e = tanhf(c0v.x + us_[i0+0]) * vs_[i0+0]
                        + tanhf(c0v.y + us_[i0+1]) * vs_[i0+1]
                        + tanhf(c0v.z + us_[i0+2]) * vs_[i0+2]
                        + tanhf(c0v.w + us_[i0+3]) * vs_[i0+3]
                        + tanhf(c1v.x + us_[i0+4]) * vs_[i0+4]
                        + tanhf(c1v.y + us_[i0+5]) * vs_[i0+5]
                        + tanhf(c1v.z + us_[i0+6]) * vs_[i0+6]
                        + tanhf(c1v.w + us_[i0+7]) * vs_[i0+7];
                e = wred(e);
                if (lane == 0) st_ag(eC_g + idx, e + p.bv[0]);
            }
            const int j = idx - 512;
            if (j >= 0 && j < t) {
                const int i0 = lane * 8;
                float e = 0.f;
                #pragma unroll
                for (int k = 0; k < 8; ++k) {
                    float hw = ld_ag(histW + (size_t)j * A_DIM + i0 + k);
                    e += tanhf(hw + ws_[i0 + k]) * v2s_[i0 + k];
                }
                e = wred(e);
                if (lane == 0) st_ag(eH_g + j, e + p.bv2[0]);
            }
        }
        gbar(bar, b, ph++);  // S1

        // ---------------- P2: softmaxes + weighted sums ----------------
        if (tid < L_CTX) aC[tid] = ld_ag(eC_g + tid);
        if (tid < t)     aH[tid] = ld_ag(eH_g + tid);
        __syncthreads();
        {
            float pC = (tid < L_CTX) ? aC[tid] : -3e38f;
            float pH = (tid < t)     ? aH[tid] : -3e38f;
            #pragma unroll
            for (int off = 32; off; off >>= 1) {
                pC = fmaxf(pC, __shfl_down(pC, off));
                pH = fmaxf(pH, __shfl_down(pH, off));
            }
            if (lane == 0) { red[wv] = pC; red[16 + wv] = pH; }
            __syncthreads();
            if (tid == 0) { float m = -3e38f; for (int g = 0; g < 16; ++g) m = fmaxf(m, red[g]); sc[0] = m; }
            if (tid == 1) { float m = -3e38f; for (int g = 0; g < 16; ++g) m = fmaxf(m, red[16 + g]); sc[1] = m; }
            __syncthreads();
            const float mC = sc[0], mH = sc[1];
            float sCp = 0.f, sHp = 0.f;
            if (tid < L_CTX) { float x = __expf(aC[tid] - mC); aC[tid] = x; sCp = x; }
            if (tid < t)     { float x = __expf(aH[tid] - mH); aH[tid] = x; sHp = x; }
            sCp = wred(sCp); sHp = wred(sHp);
            if (lane == 0) { red[wv] = sCp; red[16 + wv] = sHp; }
            __syncthreads();
            if (tid == 0) { float s = 0.f; for (int g = 0; g < 16; ++g) s += red[g]; sc[2] = s; }
            if (tid == 1) { float s = 0.f; for (int g = 0; g < 16; ++g) s += red[16 + g]; sc[3] = s; }
            __syncthreads();
            const float rC = 1.f / sc[2];
            const float rH = (t > 0) ? 1.f / sc[3] : 0.f;

            if (wv < 8) {                          // ctx_vec: dim d = b*8+wv
                const int d = b * 8 + wv;
                float s = 0.f;
                for (int l = lane; l < L_CTX; l += 64)
                    s += aC[l] * ctxT[(size_t)d * L_CTX + l];
                s = wred(s);
                if (lane == 0) {
                    float val = s * rC;
                    st_ag(ctxv + d, val);
                    p.out[(size_t)T_STEPS * H_DIM + (size_t)t * CTXD + d] = val;
                }
            }
            {                                      // h_ctx: dim d2 = b*16+wv
                const int d2 = b * 16 + wv;
                if (t == 0) {
                    if (lane == 0) st_ag(hctx + d2, 0.f);
                } else {
                    float s = 0.f;
                    for (int j = lane; j < t; j += 64)
                        s += aH[j] * ld_ag(histT + (size_t)d2 * T_STEPS + j);
                    s = wred(s);
                    if (lane == 0) st_ag(hctx + d2, s * rH);
                }
            }
        }
        gbar(bar, b, ph++);  // S2

        // ---------------- P3: big GEMV + gates ----------------
        {
            const int pt = p.parent[t];
            for (int i = tid; i < KTOT; i += NTHR) {
                float val;
                if (i < 1024)      val = ld_ag(hbuf + i);
                else if (i < 2048) val = (t > 0) ? ld_ag(hist + (size_t)pt * H_DIM + (i - 1024)) : 0.f;
                else if (i < 3072) val = ld_ag(hctx + (i - 2048));
                else               val = ld_ag(ctxv + (i - 3072));
                xs[i] = val;
            }
            __syncthreads();

            const int cl = tid & 63, kg = tid >> 6;   // 64 cols x 16 k-groups
            const us8* wp = (const us8*)(W4T + (size_t)(b * 64 + cl) * KTOT) + kg * 28;
            const float* xk = xs + kg * 224;
            float acc = 0.f;
            #pragma unroll 7
            for (int i = 0; i < 28; ++i) {
                us8 w8 = wp[i];
                #pragma unroll
                for (int j2 = 0; j2 < 8; ++j2)
                    acc += bf2f(w8[j2]) * xk[i * 8 + j2];
            }
            red[kg * 64 + cl] = acc;
            __syncthreads();
            #pragma unroll
            for (int s2 = 8; s2 >= 1; s2 >>= 1) {
                if (kg < s2) red[kg * 64 + cl] += red[(kg + s2) * 64 + cl];
                __syncthreads();
            }
            if (tid < 16) {
                const int d = b * 16 + tid;
                float zi = red[4 * tid + 0] + XWb[(size_t)t * G4 + 0 * 1024 + d];
                float zf = red[4 * tid + 1] + XWb[(size_t)t * G4 + 1 * 1024 + d];
                float zc = red[4 * tid + 2] + XWb[(size_t)t * G4 + 2 * 1024 + d];
                float zo = red[4 * tid + 3] + XWb[(size_t)t * G4 + 3 * 1024 + d];
                float cn = sigmoidf_(zf) * p.c0[d] + sigmoidf_(zi) * tanhf(zc);
                float hn = sigmoidf_(zo) * tanhf(cn);
                st_ag(hbuf + d, hn);
                st_ag(hist + (size_t)t * H_DIM + d, hn);
                st_ag(histT + (size_t)d * T_STEPS + t, hn);
                p.out[(size_t)t * H_DIM + d] = hn;
            }
        }
        gbar(bar, b, ph++);  // S3

        // ---------------- P4: u/w/histW from new h ----------------
        xs[tid] = ld_ag(hbuf + tid);
        __syncthreads();
        {
            #pragma unroll
            for (int rr = 0; rr < 2; ++rr) {
                const int r = (rr == 0) ? wv : 16 + wv;
                if (rr == 1 && wv >= 8) break;
                const int j = b * 24 + r;          // [0,1536)
                const us8* wr = (const us8*)(WT3 + (size_t)j * H_DIM) + lane * 2;
                us8 a0 = wr[0], a1 = wr[1];
                float s = 0.f;
                #pragma unroll
                for (int k = 0; k < 8; ++k) s += bf2f(a0[k]) * xs[lane * 16 + k];
                #pragma unroll
                for (int k = 0; k < 8; ++k) s += bf2f(a1[k]) * xs[lane * 16 + 8 + k];
                s = wred(s);
                if (lane == 0) {
                    if (j < A_DIM)          st_ag(u + j, s);
                    else if (j < 2 * A_DIM) st_ag(w + j - A_DIM, s + p.bhist[j - A_DIM]);
                    else                    st_ag(histW + (size_t)t * A_DIM + (j - 2 * A_DIM), s);
                }
            }
        }
        gbar(bar, b, ph++);  // S4
    }
}

// ---------- host ----------

extern "C" void kernel_launch(void* const* d_in, const int* in_sizes, int n_in,
                              void* d_out, int out_size, void* d_ws, size_t ws_size,
                              hipStream_t stream) {
    if (ws_size < (size_t)WS_FLOATS * sizeof(float)) return;  // OOB insurance

    const float* X      = (const float*)d_in[0];
    const float* ctx    = (const float*)d_in[1];
    const float* h0     = (const float*)d_in[2];
    const float* c0     = (const float*)d_in[3];
    const int*   parent = (const int*)  d_in[4];
    const float* Wx     = (const float*)d_in[5];
    const float* Uh     = (const float*)d_in[6];
    const float* Cc     = (const float*)d_in[7];
    const float* Ph     = (const float*)d_in[8];
    const float* Hh     = (const float*)d_in[9];
    const float* b4     = (const float*)d_in[10];
    const float* Wctx   = (const float*)d_in[11];
    const float* bctx   = (const float*)d_in[12];
    const float* Wh     = (const float*)d_in[13];
    const float* v      = (const float*)d_in[14];
    const float* bv     = (const float*)d_in[15];
    const float* Whist  = (const float*)d_in[16];
    const float* bhist  = (const float*)d_in[17];
    const float* Whh    = (const float*)d_in[18];
    const float* v2     = (const float*)d_in[19];
    const float* bv2    = (const float*)d_in[20];
    float* ws  = (float*)d_ws;
    float* out = (float*)d_out;

    // zero barrier counters every call (deterministic across graph replays)
    hipMemsetAsync((char*)d_ws + (size_t)OFF_BAR * sizeof(float), 0, 1024, stream);

    hipLaunchKernelGGL(k_xwb,    dim3(16, 32),     dim3(256), 0, stream, X,   Wx,   b4,   ws + OFF_XWB);
    hipLaunchKernelGGL(k_ctxw,   dim3(2, 25),      dim3(256), 0, stream, ctx, Wctx, bctx, ws + OFF_CTXW);
    hipLaunchKernelGGL(k_trg,    dim3(7, 16),      dim3(256), 0, stream, ctx, ws + OFF_CTXT);
    hipLaunchKernelGGL(k_packW4, dim3(112, 32, 4), dim3(256), 0, stream, Uh, Ph, Hh, Cc,
                       (unsigned short*)(ws + OFF_W4T));
    hipLaunchKernelGGL(k_packW3, dim3(32, 16, 3),  dim3(256), 0, stream, Wh, Whh, Whist,
                       (unsigned short*)(ws + OFF_WT3));

    LP p{c0, v, v2, bv, bv2, bhist, h0, parent, ws, out};
    hipLaunchKernelGGL(lstm_loop, dim3(NBLK), dim3(NTHR), 0, stream, p);
}